// Round 14
// baseline (69.633 us; speedup 1.0000x reference)
//
#include <hip/hip_runtime.h>

#define BB 4
#define NN 4
#define TT 4
#define AA 128
#define DD 64
#define HWD 36864              // 192*192
#define NPTS (BB * NN * HWD)   // 589824
#define NG (BB * TT * AA)      // 2048
#define CHUNKS 256
#define CPTS (HWD / CHUNKS)    // 144
#define NBLK (BB * TT * CHUNKS)  // 4096

__device__ __constant__ int c_ti[4] = {0, 0, 0, 1};
__device__ __constant__ int c_tj[4] = {1, 1, 2, 2};
__device__ __constant__ int c_tk[4] = {2, 3, 3, 3};

// Scalar-pipe (SMEM) view of read-only global data (wave-uniform addresses).
typedef const __attribute__((address_space(4))) float cfloat;

// Order-monotone float<->uint mapping: f1 < f2  <=>  fmap(f1) < fmap(f2).
__device__ __forceinline__ unsigned int fmap(float f) {
    const unsigned int b = __float_as_uint(f);
    return (b & 0x80000000u) ? ~b : (b | 0x80000000u);
}
__device__ __forceinline__ float funmap(unsigned int m) {
    const unsigned int b = (m & 0x80000000u) ? (m ^ 0x80000000u) : ~m;
    return __uint_as_float(m & 0x80000000u ? (m ^ 0x80000000u) : ~m);
}

// ---------------------------------------------------------------------------
// K0: prep — pack pts into float4 (x,y,z,|p|^2) for images 1..3 only (image 0
// is only ever a query source, and queries read raw pts). Also arms slots/ctr
// with plain stores (kernel boundary publishes). s2 expression identical
// (contract off) to R13.
// ---------------------------------------------------------------------------
__global__ __launch_bounds__(256) void
prep_kernel(const float* __restrict__ pts, float4* __restrict__ pk4,
            unsigned long long* __restrict__ slots,   // slot1|slot2, 2*NG
            unsigned int* __restrict__ ctr) {
#pragma clang fp contract(off)
    const int idx = blockIdx.x * 256 + threadIdx.x;
    if (idx < NPTS && ((idx / HWD) & 3) != 0) {
        const float x = pts[idx * 3 + 0];
        const float y = pts[idx * 3 + 1];
        const float z = pts[idx * 3 + 2];
        pk4[idx] = make_float4(x, y, z, x * x + y * y + z * z);
    }
    if (blockIdx.x == 0) {
        for (int s = threadIdx.x; s < 2 * NG; s += 256)
            slots[s] = 0xFFFFFFFFFFFFFFFFull;        // +inf sentinel
        if (threadIdx.x == 0) ctr[0] = 0xFFFFFFFFu;  // after k incs: k-1
    }
}

// ---------------------------------------------------------------------------
// K1: scan1. Block=(bt,chunk), 128 threads = 128 anchor queries; queries read
// RAW pts (need only -2*q); wave-uniform packed float4 stream on the scalar
// pipe. Key = s2 - 2*dot; partial published via u64 atomicMin:
//   val = (fmap(key) << 32) | global_point_idx
// -> min key, smaller-index tie-break == numpy first-occurrence argmin.
// CHUNKS=256 -> 8 waves/SIMD for latency hiding.
// ---------------------------------------------------------------------------
__global__ __launch_bounds__(128) void
scan1_kernel(const float* __restrict__ pts,
             const float4* __restrict__ pk4,
             const int* __restrict__ anchor_idx,
             unsigned long long* __restrict__ slot1) {
    const int chunk = blockIdx.x & (CHUNKS - 1);
    const int bt = blockIdx.x >> 8;
    const int t = bt & 3;
    const int b = bt >> 2;
    const int g = bt * AA + threadIdx.x;

    const int qpix = anchor_idx[g];
    const float* qp = pts + ((long)(b * NN + c_ti[t]) * HWD + qpix) * 3;
    const float m2x = -2.0f * qp[0];
    const float m2y = -2.0f * qp[1];
    const float m2z = -2.0f * qp[2];

    const float4* sp = pk4 + (b * NN + c_tj[t]) * HWD + chunk * CPTS;
    cfloat* sps = (cfloat*)(unsigned long long)sp;   // scalar-pipe stream

    float best = 3.4e38f;
    int besti = 0;
#pragma unroll 8
    for (int p = 0; p < CPTS; ++p) {
        const float x = sps[4 * p + 0];
        const float y = sps[4 * p + 1];
        const float z = sps[4 * p + 2];
        const float w = sps[4 * p + 3];
        const float key = fmaf(x, m2x, fmaf(y, m2y, fmaf(z, m2z, w)));
        if (key < best) { best = key; besti = p; }   // ascending -> first occ
    }
    const unsigned long long v =
        ((unsigned long long)fmap(best) << 32) |
        (unsigned int)(chunk * CPTS + besti);
    atomicMin(&slot1[g], v);   // non-returning: fire-and-forget
}

// ---------------------------------------------------------------------------
// K2: scan2. idx_j from slot1 low bits; query = raw pts of image tj.
// ---------------------------------------------------------------------------
__global__ __launch_bounds__(128) void
scan2_kernel(const float* __restrict__ pts,
             const float4* __restrict__ pk4,
             const unsigned long long* __restrict__ slot1,
             unsigned long long* __restrict__ slot2) {
    const int tid = threadIdx.x;
    const int chunk = blockIdx.x & (CHUNKS - 1);
    const int bt = blockIdx.x >> 8;
    const int t = bt & 3;
    const int b = bt >> 2;
    const int g = bt * AA + tid;

    const int ij = (int)(slot1[g] & 0xFFFFFFFFull);
    const float* jp = pts + ((long)(b * NN + c_tj[t]) * HWD + ij) * 3;
    const float m2x = -2.0f * jp[0];
    const float m2y = -2.0f * jp[1];
    const float m2z = -2.0f * jp[2];

    const float4* sp = pk4 + (b * NN + c_tk[t]) * HWD + chunk * CPTS;
    cfloat* sps = (cfloat*)(unsigned long long)sp;

    float best = 3.4e38f;
    int besti = 0;
#pragma unroll 8
    for (int p = 0; p < CPTS; ++p) {
        const float x = sps[4 * p + 0];
        const float y = sps[4 * p + 1];
        const float z = sps[4 * p + 2];
        const float w = sps[4 * p + 3];
        const float key = fmaf(x, m2x, fmaf(y, m2y, fmaf(z, m2z, w)));
        if (key < best) { best = key; besti = p; }
    }
    const unsigned long long v =
        ((unsigned long long)fmap(best) << 32) |
        (unsigned int)(chunk * CPTS + besti);
    atomicMin(&slot2[g], v);
}

// ---------------------------------------------------------------------------
// K3: pass3 + chained final (16 blocks, 128 threads). R13 verbatim (passed).
// ---------------------------------------------------------------------------
__global__ __launch_bounds__(128) void
pass3_kernel(const float* __restrict__ pts,
             const float* __restrict__ feats,
             const int* __restrict__ anchor_idx,
             const unsigned long long* __restrict__ slot1,
             const unsigned long long* __restrict__ slot2,
             float* __restrict__ loss_bt,
             float* __restrict__ batch_ok,
             unsigned int* __restrict__ ctr,
             float* __restrict__ out) {
#pragma clang fp contract(off)
    const int bt = blockIdx.x;
    const int t = bt & 3;
    const int b = bt >> 2;
    const int i = c_ti[t];
    const int k = c_tk[t];
    const int tid = threadIdx.x;
    const int g = bt * AA + tid;

    // anchor point & |q|^2 (raw pts)
    const int ai = anchor_idx[g];
    const float* ap = pts + ((long)(b * NN + i) * HWD + ai) * 3;
    const float ax = ap[0], ay = ap[1], az = ap[2];
    const float sq = ax * ax + ay * ay + az * az;

    // min_ij from slot1
    const unsigned long long s1 = slot1[g];
    const float min_ij = sqrtf(fmaxf(funmap((unsigned int)(s1 >> 32)) + sq, 0.0f));
    const int ij = (int)(s1 & 0xFFFFFFFFull);

    // min_jk from slot2 (needs |pj|^2)
    const float* jp = pts + ((long)(b * NN + c_tj[t]) * HWD + ij) * 3;
    const float jx = jp[0], jy = jp[1], jz = jp[2];
    const float sqj = jx * jx + jy * jy + jz * jz;
    const unsigned long long s2v = slot2[g];
    const float min_jk =
        sqrtf(fmaxf(funmap((unsigned int)(s2v >> 32)) + sqj, 0.0f));
    const int ik = (int)(s2v & 0xFFFFFFFFull);

    // dki
    __shared__ float aps[AA][3];
    aps[tid][0] = ax;
    aps[tid][1] = ay;
    aps[tid][2] = az;
    const float* kp = pts + ((long)(b * NN + k) * HWD + ik) * 3;
    const float kx = kp[0], ky = kp[1], kz = kp[2];
    const float sk = kx * kx + ky * ky + kz * kz;
    __syncthreads();

    float best = 3.4e38f;
    int besti = 0;
    for (int a2 = 0; a2 < AA; ++a2) {
        const float qx = aps[a2][0], qy = aps[a2][1], qz = aps[a2][2];
        const float s2 = qx * qx + qy * qy + qz * qz;
        const float dot = kx * qx + ky * qy + kz * qz;
        const float d2 = (sk + s2) - 2.0f * dot;
        if (d2 < best) { best = d2; besti = a2; }
    }
    const float min_ki = sqrtf(fmaxf(best, 0.0f));

    const int valid =
        (min_ij < 0.3f) && (min_jk < 0.3f) && (min_ki < 0.3f);

    // feat_ret: reference quirk — raw pixel index besti in [0,128).
    // float4 loads; accumulation order identical to the scalar d-loop.
    const float4* fr4 =
        (const float4*)(feats + ((long)(b * NN + i) * HWD + besti) * DD);
    const float4* fa4 =
        (const float4*)(feats + ((long)(b * NN + i) * HWD + ai) * DD);
    float snr = 0.0f, sna = 0.0f;
#pragma unroll
    for (int r = 0; r < 16; ++r) {
        const float4 v = fr4[r];
        snr = snr + v.x * v.x; snr = snr + v.y * v.y;
        snr = snr + v.z * v.z; snr = snr + v.w * v.w;
    }
#pragma unroll
    for (int r = 0; r < 16; ++r) {
        const float4 v = fa4[r];
        sna = sna + v.x * v.x; sna = sna + v.y * v.y;
        sna = sna + v.z * v.z; sna = sna + v.w * v.w;
    }
    const float nr = fmaxf(sqrtf(snr), 1e-12f);
    const float na = fmaxf(sqrtf(sna), 1e-12f);
    float se = 0.0f;
#pragma unroll
    for (int r = 0; r < 16; ++r) {
        const float4 u = fr4[r];
        const float4 v = fa4[r];
        float x;
        x = u.x / nr - v.x / na; se = se + x * x;
        x = u.y / nr - v.y / na; se = se + x * x;
        x = u.z / nr - v.z / na; se = se + x * x;
        x = u.w / nr - v.w / na; se = se + x * x;
    }

    __shared__ float sred[2][AA];
    sred[0][tid] = (float)valid;
    sred[1][tid] = valid ? se : 0.0f;
    __syncthreads();
    for (int s = 64; s > 0; s >>= 1) {
        if (tid < s) {
            sred[0][tid] += sred[0][tid + s];
            sred[1][tid] += sred[1][tid + s];
        }
        __syncthreads();
    }

    __shared__ int s_fin;
    if (tid == 0) {
        const float cnt = sred[0][0];
        const float lbt = (cnt > 0.0f)
                              ? sred[1][0] / (fmaxf(cnt, 1.0f) * (float)DD)
                              : 0.0f;
        const float ok = (cnt >= 5.0f) ? 1.0f : 0.0f;
        atomicExch(&loss_bt[bt], lbt);     // device-scope write-through
        atomicExch(&batch_ok[bt], ok);
        __threadfence();                   // only 16 blocks — amortized
        s_fin = (atomicAdd(ctr, 1u) == 14u) ? 1 : 0;   // 16th arrival
    }
    __syncthreads();
    if (!s_fin) return;

    __shared__ float sok[16], slo[16];
    if (tid < 16) {
        sok[tid] = atomicAdd(&batch_ok[tid], 0.0f);   // coherent loads
        slo[tid] = atomicAdd(&loss_bt[tid], 0.0f);
    }
    __syncthreads();
    if (tid == 0) {
        float s = 0.0f;
        for (int tt = 0; tt < TT; ++tt) {
            float tc = 0.0f, sl = 0.0f;
            for (int bb = 0; bb < BB; ++bb) {
                const float okv = sok[bb * TT + tt];
                tc += okv;
                sl += slo[bb * TT + tt] * okv;
            }
            s += (tc > 0.0f) ? sl / fmaxf(tc, 1.0f) : 0.0f;
        }
        out[0] = s / (float)TT;
    }
}

extern "C" void kernel_launch(void* const* d_in, const int* in_sizes, int n_in,
                              void* d_out, int out_size, void* d_ws,
                              size_t ws_size, hipStream_t stream) {
    const float* feats = (const float*)d_in[0];   // (B,N,H,W,D) f32
    const float* pts = (const float*)d_in[1];     // (B,N,H,W,3) f32
    const int* anchor = (const int*)d_in[2];      // (B,T,A) i32
    float* out = (float*)d_out;

    float* ws = (float*)d_ws;
    float4* pk4 = (float4*)ws;                               // 9.4 MB
    unsigned long long* slot1 = (unsigned long long*)(ws + NPTS * 4);
    unsigned long long* slot2 = slot1 + NG;
    unsigned int* ctr = (unsigned int*)(slot2 + NG);         // 1 u32
    float* loss_bt = (float*)(ctr + 1);                      // 16 f32
    float* batch_ok = loss_bt + 16;                          // 16 f32

    prep_kernel<<<(NPTS + 255) / 256, 256, 0, stream>>>(pts, pk4, slot1, ctr);
    scan1_kernel<<<NBLK, 128, 0, stream>>>(pts, pk4, anchor, slot1);
    scan2_kernel<<<NBLK, 128, 0, stream>>>(pts, pk4, slot1, slot2);
    pass3_kernel<<<BB * TT, 128, 0, stream>>>(pts, feats, anchor, slot1,
                                              slot2, loss_bt, batch_ok, ctr,
                                              out);
}

// Round 15
// 65.654 us; speedup vs baseline: 1.0606x; 1.0606x over previous
//
#include <hip/hip_runtime.h>

#define BB 4
#define NN 4
#define TT 4
#define AA 128
#define DD 64
#define HWD 36864              // 192*192
#define NPTS (BB * NN * HWD)   // 589824
#define NG (BB * TT * AA)      // 2048
#define CHUNKS 128
#define CPTS (HWD / CHUNKS)    // 288
#define HALF (CPTS / 2)        // 144
#define NBLK (BB * TT * CHUNKS)  // 2048

__device__ __constant__ int c_ti[4] = {0, 0, 0, 1};
__device__ __constant__ int c_tj[4] = {1, 1, 2, 2};
__device__ __constant__ int c_tk[4] = {2, 3, 3, 3};

// Scalar-pipe (SMEM) view of read-only global data (wave-uniform addresses).
typedef const __attribute__((address_space(4))) float cfloat;

// Order-monotone float<->uint mapping: f1 < f2  <=>  fmap(f1) < fmap(f2).
__device__ __forceinline__ unsigned int fmap(float f) {
    const unsigned int b = __float_as_uint(f);
    return (b & 0x80000000u) ? ~b : (b | 0x80000000u);
}
__device__ __forceinline__ float funmap(unsigned int m) {
    return __uint_as_float((m & 0x80000000u) ? (m ^ 0x80000000u) : ~m);
}

// ---------------------------------------------------------------------------
// K0: prep — pack pts into float4 (x,y,z,|p|^2) for images 1..3 (image 0 is
// only a query source; queries read raw pts). Arms slots/ctr with plain
// stores (kernel boundary publishes). s2 expression contract-off, identical
// to R13/R14 (passed).
// ---------------------------------------------------------------------------
__global__ __launch_bounds__(256) void
prep_kernel(const float* __restrict__ pts, float4* __restrict__ pk4,
            unsigned long long* __restrict__ slots,   // slot1|slot2, 2*NG
            unsigned int* __restrict__ ctr) {
#pragma clang fp contract(off)
    const int idx = blockIdx.x * 256 + threadIdx.x;
    if (idx < NPTS && ((idx / HWD) & 3) != 0) {
        const float x = pts[idx * 3 + 0];
        const float y = pts[idx * 3 + 1];
        const float z = pts[idx * 3 + 2];
        pk4[idx] = make_float4(x, y, z, x * x + y * y + z * z);
    }
    if (blockIdx.x == 0) {
        for (int s = threadIdx.x; s < 2 * NG; s += 256)
            slots[s] = 0xFFFFFFFFFFFFFFFFull;        // +inf sentinel
        if (threadIdx.x == 0) ctr[0] = 0xFFFFFFFFu;  // after k incs: k-1
    }
}

// ---------------------------------------------------------------------------
// Scan core: two independent (best,besti) chains interleaved (2x ILP on the
// serial cmp/cndmask dependency), merged with strict < so chain A (lower
// indices) wins ties == numpy first-occurrence argmin. Key = s2 - 2*dot,
// fmaf chain identical to R13/R14.
// ---------------------------------------------------------------------------
__device__ __forceinline__ unsigned long long
scan_chunk(cfloat* sps, float m2x, float m2y, float m2z, int chunk) {
    float bestA = 3.4e38f, bestB = 3.4e38f;
    int biA = 0, biB = 0;
#pragma unroll 4
    for (int p = 0; p < HALF; ++p) {
        const float xa = sps[4 * p + 0];
        const float ya = sps[4 * p + 1];
        const float za = sps[4 * p + 2];
        const float wa = sps[4 * p + 3];
        const int pb = p + HALF;
        const float xb = sps[4 * pb + 0];
        const float yb = sps[4 * pb + 1];
        const float zb = sps[4 * pb + 2];
        const float wb = sps[4 * pb + 3];
        const float ka = fmaf(xa, m2x, fmaf(ya, m2y, fmaf(za, m2z, wa)));
        const float kb = fmaf(xb, m2x, fmaf(yb, m2y, fmaf(zb, m2z, wb)));
        if (ka < bestA) { bestA = ka; biA = p; }    // ascending -> first occ
        if (kb < bestB) { bestB = kb; biB = pb; }
    }
    // merge: strict < keeps A on ties; A's indices are all lower than B's.
    float best = bestA;
    int besti = biA;
    if (bestB < bestA) { best = bestB; besti = biB; }
    return ((unsigned long long)fmap(best) << 32) |
           (unsigned int)(chunk * CPTS + besti);
}

// ---------------------------------------------------------------------------
// K1: scan1. Block=(bt,chunk), 128 threads = 128 anchor queries; queries read
// RAW pts; wave-uniform packed float4 stream on the scalar pipe. Partial
// published via u64 atomicMin (min key, min-idx tie-break = first occurrence).
// ---------------------------------------------------------------------------
__global__ __launch_bounds__(128) void
scan1_kernel(const float* __restrict__ pts,
             const float4* __restrict__ pk4,
             const int* __restrict__ anchor_idx,
             unsigned long long* __restrict__ slot1) {
    const int chunk = blockIdx.x & (CHUNKS - 1);
    const int bt = blockIdx.x >> 7;
    const int t = bt & 3;
    const int b = bt >> 2;
    const int g = bt * AA + threadIdx.x;

    const int qpix = anchor_idx[g];
    const float* qp = pts + ((long)(b * NN + c_ti[t]) * HWD + qpix) * 3;
    const float m2x = -2.0f * qp[0];
    const float m2y = -2.0f * qp[1];
    const float m2z = -2.0f * qp[2];

    const float4* sp = pk4 + (b * NN + c_tj[t]) * HWD + chunk * CPTS;
    cfloat* sps = (cfloat*)(unsigned long long)sp;   // scalar-pipe stream

    atomicMin(&slot1[g], scan_chunk(sps, m2x, m2y, m2z, chunk));
}

// ---------------------------------------------------------------------------
// K2: scan2. idx_j from slot1 low bits; query = raw pts of image tj.
// ---------------------------------------------------------------------------
__global__ __launch_bounds__(128) void
scan2_kernel(const float* __restrict__ pts,
             const float4* __restrict__ pk4,
             const unsigned long long* __restrict__ slot1,
             unsigned long long* __restrict__ slot2) {
    const int tid = threadIdx.x;
    const int chunk = blockIdx.x & (CHUNKS - 1);
    const int bt = blockIdx.x >> 7;
    const int t = bt & 3;
    const int b = bt >> 2;
    const int g = bt * AA + tid;

    const int ij = (int)(slot1[g] & 0xFFFFFFFFull);
    const float* jp = pts + ((long)(b * NN + c_tj[t]) * HWD + ij) * 3;
    const float m2x = -2.0f * jp[0];
    const float m2y = -2.0f * jp[1];
    const float m2z = -2.0f * jp[2];

    const float4* sp = pk4 + (b * NN + c_tk[t]) * HWD + chunk * CPTS;
    cfloat* sps = (cfloat*)(unsigned long long)sp;

    atomicMin(&slot2[g], scan_chunk(sps, m2x, m2y, m2z, chunk));
}

// ---------------------------------------------------------------------------
// K3: pass3 + chained final (16 blocks, 128 threads). R13/R14 verbatim.
// ---------------------------------------------------------------------------
__global__ __launch_bounds__(128) void
pass3_kernel(const float* __restrict__ pts,
             const float* __restrict__ feats,
             const int* __restrict__ anchor_idx,
             const unsigned long long* __restrict__ slot1,
             const unsigned long long* __restrict__ slot2,
             float* __restrict__ loss_bt,
             float* __restrict__ batch_ok,
             unsigned int* __restrict__ ctr,
             float* __restrict__ out) {
#pragma clang fp contract(off)
    const int bt = blockIdx.x;
    const int t = bt & 3;
    const int b = bt >> 2;
    const int i = c_ti[t];
    const int k = c_tk[t];
    const int tid = threadIdx.x;
    const int g = bt * AA + tid;

    // anchor point & |q|^2 (raw pts)
    const int ai = anchor_idx[g];
    const float* ap = pts + ((long)(b * NN + i) * HWD + ai) * 3;
    const float ax = ap[0], ay = ap[1], az = ap[2];
    const float sq = ax * ax + ay * ay + az * az;

    // min_ij from slot1
    const unsigned long long s1 = slot1[g];
    const float min_ij = sqrtf(fmaxf(funmap((unsigned int)(s1 >> 32)) + sq, 0.0f));
    const int ij = (int)(s1 & 0xFFFFFFFFull);

    // min_jk from slot2 (needs |pj|^2)
    const float* jp = pts + ((long)(b * NN + c_tj[t]) * HWD + ij) * 3;
    const float jx = jp[0], jy = jp[1], jz = jp[2];
    const float sqj = jx * jx + jy * jy + jz * jz;
    const unsigned long long s2v = slot2[g];
    const float min_jk =
        sqrtf(fmaxf(funmap((unsigned int)(s2v >> 32)) + sqj, 0.0f));
    const int ik = (int)(s2v & 0xFFFFFFFFull);

    // dki
    __shared__ float aps[AA][3];
    aps[tid][0] = ax;
    aps[tid][1] = ay;
    aps[tid][2] = az;
    const float* kp = pts + ((long)(b * NN + k) * HWD + ik) * 3;
    const float kx = kp[0], ky = kp[1], kz = kp[2];
    const float sk = kx * kx + ky * ky + kz * kz;
    __syncthreads();

    float best = 3.4e38f;
    int besti = 0;
    for (int a2 = 0; a2 < AA; ++a2) {
        const float qx = aps[a2][0], qy = aps[a2][1], qz = aps[a2][2];
        const float s2 = qx * qx + qy * qy + qz * qz;
        const float dot = kx * qx + ky * qy + kz * qz;
        const float d2 = (sk + s2) - 2.0f * dot;
        if (d2 < best) { best = d2; besti = a2; }
    }
    const float min_ki = sqrtf(fmaxf(best, 0.0f));

    const int valid =
        (min_ij < 0.3f) && (min_jk < 0.3f) && (min_ki < 0.3f);

    // feat_ret: reference quirk — raw pixel index besti in [0,128).
    // float4 loads; accumulation order identical to the scalar d-loop.
    const float4* fr4 =
        (const float4*)(feats + ((long)(b * NN + i) * HWD + besti) * DD);
    const float4* fa4 =
        (const float4*)(feats + ((long)(b * NN + i) * HWD + ai) * DD);
    float snr = 0.0f, sna = 0.0f;
#pragma unroll
    for (int r = 0; r < 16; ++r) {
        const float4 v = fr4[r];
        snr = snr + v.x * v.x; snr = snr + v.y * v.y;
        snr = snr + v.z * v.z; snr = snr + v.w * v.w;
    }
#pragma unroll
    for (int r = 0; r < 16; ++r) {
        const float4 v = fa4[r];
        sna = sna + v.x * v.x; sna = sna + v.y * v.y;
        sna = sna + v.z * v.z; sna = sna + v.w * v.w;
    }
    const float nr = fmaxf(sqrtf(snr), 1e-12f);
    const float na = fmaxf(sqrtf(sna), 1e-12f);
    float se = 0.0f;
#pragma unroll
    for (int r = 0; r < 16; ++r) {
        const float4 u = fr4[r];
        const float4 v = fa4[r];
        float x;
        x = u.x / nr - v.x / na; se = se + x * x;
        x = u.y / nr - v.y / na; se = se + x * x;
        x = u.z / nr - v.z / na; se = se + x * x;
        x = u.w / nr - v.w / na; se = se + x * x;
    }

    __shared__ float sred[2][AA];
    sred[0][tid] = (float)valid;
    sred[1][tid] = valid ? se : 0.0f;
    __syncthreads();
    for (int s = 64; s > 0; s >>= 1) {
        if (tid < s) {
            sred[0][tid] += sred[0][tid + s];
            sred[1][tid] += sred[1][tid + s];
        }
        __syncthreads();
    }

    __shared__ int s_fin;
    if (tid == 0) {
        const float cnt = sred[0][0];
        const float lbt = (cnt > 0.0f)
                              ? sred[1][0] / (fmaxf(cnt, 1.0f) * (float)DD)
                              : 0.0f;
        const float ok = (cnt >= 5.0f) ? 1.0f : 0.0f;
        atomicExch(&loss_bt[bt], lbt);     // device-scope write-through
        atomicExch(&batch_ok[bt], ok);
        __threadfence();                   // only 16 blocks — amortized
        s_fin = (atomicAdd(ctr, 1u) == 14u) ? 1 : 0;   // 16th arrival
    }
    __syncthreads();
    if (!s_fin) return;

    __shared__ float sok[16], slo[16];
    if (tid < 16) {
        sok[tid] = atomicAdd(&batch_ok[tid], 0.0f);   // coherent loads
        slo[tid] = atomicAdd(&loss_bt[tid], 0.0f);
    }
    __syncthreads();
    if (tid == 0) {
        float s = 0.0f;
        for (int tt = 0; tt < TT; ++tt) {
            float tc = 0.0f, sl = 0.0f;
            for (int bb = 0; bb < BB; ++bb) {
                const float okv = sok[bb * TT + tt];
                tc += okv;
                sl += slo[bb * TT + tt] * okv;
            }
            s += (tc > 0.0f) ? sl / fmaxf(tc, 1.0f) : 0.0f;
        }
        out[0] = s / (float)TT;
    }
}

extern "C" void kernel_launch(void* const* d_in, const int* in_sizes, int n_in,
                              void* d_out, int out_size, void* d_ws,
                              size_t ws_size, hipStream_t stream) {
    const float* feats = (const float*)d_in[0];   // (B,N,H,W,D) f32
    const float* pts = (const float*)d_in[1];     // (B,N,H,W,3) f32
    const int* anchor = (const int*)d_in[2];      // (B,T,A) i32
    float* out = (float*)d_out;

    float* ws = (float*)d_ws;
    float4* pk4 = (float4*)ws;                               // 9.4 MB
    unsigned long long* slot1 = (unsigned long long*)(ws + NPTS * 4);
    unsigned long long* slot2 = slot1 + NG;
    unsigned int* ctr = (unsigned int*)(slot2 + NG);         // 1 u32
    float* loss_bt = (float*)(ctr + 1);                      // 16 f32
    float* batch_ok = loss_bt + 16;                          // 16 f32

    prep_kernel<<<(NPTS + 255) / 256, 256, 0, stream>>>(pts, pk4, slot1, ctr);
    scan1_kernel<<<NBLK, 128, 0, stream>>>(pts, pk4, anchor, slot1);
    scan2_kernel<<<NBLK, 128, 0, stream>>>(pts, pk4, slot1, slot2);
    pass3_kernel<<<BB * TT, 128, 0, stream>>>(pts, feats, anchor, slot1,
                                              slot2, loss_bt, batch_ok, ctr,
                                              out);
}